// Round 1
// baseline (374.613 us; speedup 1.0000x reference)
//
#include <hip/hip_runtime.h>
#include <hip/hip_bf16.h>
#include <cstdio>

#define B_  64
#define I_  2048
#define J_  16
#define N_  64
#define D_  16
#define K_  1024   // N_*D_
#define ITILE 64
#define ICH (I_/ITILE)   // 32 i-chunks

__device__ __forceinline__ float bf2f(unsigned short h) {
  return __uint_as_float(((unsigned int)h) << 16);
}
__device__ __forceinline__ unsigned short f2bf(float f) {
  unsigned int u = __float_as_uint(f);
  u += 0x7fffu + ((u >> 16) & 1u);   // RNE
  return (unsigned short)(u >> 16);
}

// One workgroup per in_capsule i. W[i] (16x1024) held in registers (16 float4/thread),
// reused across all 64 batches. u_hat stored bf16.
__global__ __launch_bounds__(256) void project_k(const float* __restrict__ x,
                                                 const float* __restrict__ W,
                                                 __hip_bfloat16* __restrict__ uh) {
  const int i = blockIdx.x;
  const int t = threadIdx.x;          // k = 4t..4t+3
  const float4* Wp = (const float4*)(W + (size_t)i * (J_ * K_));
  float4 w[J_];
#pragma unroll
  for (int j = 0; j < J_; ++j) w[j] = Wp[j * (K_ / 4) + t];

  for (int b = 0; b < B_; ++b) {
    const float* xr = x + ((size_t)b * I_ + i) * J_;   // wave-uniform address
    float4 acc = {0.f, 0.f, 0.f, 0.f};
#pragma unroll
    for (int j = 0; j < J_; ++j) {
      float xj = xr[j];
      acc.x += xj * w[j].x; acc.y += xj * w[j].y;
      acc.z += xj * w[j].z; acc.w += xj * w[j].w;
    }
    ushort4 s;
    s.x = f2bf(acc.x); s.y = f2bf(acc.y); s.z = f2bf(acc.z); s.w = f2bf(acc.w);
    *(ushort4*)((unsigned short*)uh + ((size_t)b * I_ + i) * K_ + t * 4) = s;
  }
}

// One workgroup per (batch b, i-chunk). Thread owns 4 consecutive k; 4 lanes per n.
// MODE 0: c = 1/64 (softmax of zeros) -> plain sum, scaled at the end.
// MODE 1: a = u.v ; b1 = a (store) ; c = softmax_n(b1)
// MODE 2: a = u.v ; b2 = b1 + a    ; c = softmax_n(b2)
template <int MODE>
__global__ __launch_bounds__(256) void route_k(const __hip_bfloat16* __restrict__ uh,
                                               const float* __restrict__ v_in,
                                               const float* __restrict__ b_prev,
                                               float* __restrict__ b_out,
                                               float* __restrict__ s_out) {
  const int t  = threadIdx.x;
  const int b  = blockIdx.y;
  const int ic = blockIdx.x;
  const int w  = t >> 6;
  const int l  = t & 63;
  const int k0 = t * 4;
  const int n  = t >> 2;

  __shared__ float v_lds[K_];
  __shared__ float red_max[4], red_sum[4];

  if (MODE >= 1) {
    *(float4*)&v_lds[k0] = *(const float4*)&v_in[b * K_ + k0];
    __syncthreads();
  }

  const unsigned short* up = (const unsigned short*)uh;
  float s0 = 0.f, s1 = 0.f, s2 = 0.f, s3 = 0.f;

  int i = ic * ITILE;
  ushort4 q = *(const ushort4*)(up + ((size_t)b * I_ + i) * K_ + k0);

  for (int ii = 0; ii < ITILE; ++ii) {
    i = ic * ITILE + ii;
    ushort4 qn = q;
    if (ii + 1 < ITILE)   // one-deep prefetch
      qn = *(const ushort4*)(up + ((size_t)b * I_ + (i + 1)) * K_ + k0);

    float u0 = bf2f(q.x), u1 = bf2f(q.y), u2 = bf2f(q.z), u3 = bf2f(q.w);

    if (MODE == 0) {
      s0 += u0; s1 += u1; s2 += u2; s3 += u3;
      q = qn;
      continue;
    }

    // agreement a[n] = sum_d u*v  (reduce across the 4 lanes sharing n)
    float ap = u0 * v_lds[k0] + u1 * v_lds[k0 + 1] + u2 * v_lds[k0 + 2] + u3 * v_lds[k0 + 3];
    ap += __shfl_xor(ap, 1);
    ap += __shfl_xor(ap, 2);

    float bl = ap;
    if (MODE == 2) bl += b_prev[((size_t)b * I_ + i) * N_ + n];
    if (MODE == 1) {
      if ((t & 3) == 0) b_out[((size_t)b * I_ + i) * N_ + n] = bl;
    }

    // softmax over n=0..63: wave covers 16 n's (bits 2..5 of lane), LDS joins 4 waves
    float m = bl;
    m = fmaxf(m, __shfl_xor(m, 4));
    m = fmaxf(m, __shfl_xor(m, 8));
    m = fmaxf(m, __shfl_xor(m, 16));
    m = fmaxf(m, __shfl_xor(m, 32));
    if (l == 0) red_max[w] = m;
    __syncthreads();
    float gmax = fmaxf(fmaxf(red_max[0], red_max[1]), fmaxf(red_max[2], red_max[3]));

    float e = __expf(bl - gmax);
    float ss = e;
    ss += __shfl_xor(ss, 4);
    ss += __shfl_xor(ss, 8);
    ss += __shfl_xor(ss, 16);
    ss += __shfl_xor(ss, 32);
    if (l == 0) red_sum[w] = ss;
    __syncthreads();
    float denom = red_sum[0] + red_sum[1] + red_sum[2] + red_sum[3];
    float c = e / denom;

    s0 += c * u0; s1 += c * u1; s2 += c * u2; s3 += c * u3;
    q = qn;
  }

  const float scale = (MODE == 0) ? (1.0f / 64.0f) : 1.0f;
  atomicAdd(&s_out[b * K_ + k0 + 0], s0 * scale);
  atomicAdd(&s_out[b * K_ + k0 + 1], s1 * scale);
  atomicAdd(&s_out[b * K_ + k0 + 2], s2 * scale);
  atomicAdd(&s_out[b * K_ + k0 + 3], s3 * scale);
}

// v = squash(s + bias); norm over d=16 (4 lanes per n)
__global__ __launch_bounds__(256) void squash_k(const float* __restrict__ s_in,
                                                const float* __restrict__ bias,
                                                float* __restrict__ v_out) {
  const int b = blockIdx.x, t = threadIdx.x, k0 = t * 4;
  float4 s = *(const float4*)&s_in[b * K_ + k0];
  float4 bb = *(const float4*)&bias[k0];
  s.x += bb.x; s.y += bb.y; s.z += bb.z; s.w += bb.w;
  float p = s.x * s.x + s.y * s.y + s.z * s.z + s.w * s.w;
  p += __shfl_xor(p, 1);
  p += __shfl_xor(p, 2);
  float n2 = p + 1e-7f;          // norm^2 (includes EPS, matching reference)
  float nrm = sqrtf(n2);
  float f = nrm / (1.0f + n2);   // == norm_sq/(1+norm_sq)/norm
  float4 o = {s.x * f, s.y * f, s.z * f, s.w * f};
  *(float4*)&v_out[b * K_ + k0] = o;
}

extern "C" void kernel_launch(void* const* d_in, const int* in_sizes, int n_in,
                              void* d_out, int out_size, void* d_ws, size_t ws_size,
                              hipStream_t stream) {
  const float* x    = (const float*)d_in[0];
  const float* W    = (const float*)d_in[1];
  const float* bias = (const float*)d_in[2];
  float* out = (float*)d_out;

  char* ws = (char*)d_ws;
  size_t off = 0;
  __hip_bfloat16* uh = (__hip_bfloat16*)(ws + off); off += (size_t)B_ * I_ * K_ * 2;  // 268 MB
  float* b1 = (float*)(ws + off); off += (size_t)B_ * I_ * N_ * 4;                    // 33.5 MB
  float* s0 = (float*)(ws + off); off += (size_t)B_ * K_ * 4;
  float* s1 = (float*)(ws + off); off += (size_t)B_ * K_ * 4;
  float* s2 = (float*)(ws + off); off += (size_t)B_ * K_ * 4;
  float* v0 = (float*)(ws + off); off += (size_t)B_ * K_ * 4;
  float* v1 = (float*)(ws + off); off += (size_t)B_ * K_ * 4;

  if (ws_size < off)
    fprintf(stderr, "ClassCapsule: ws_size=%zu < needed=%zu — expect corruption\n", ws_size, off);

  // zero the three s accumulators (contiguous)
  hipMemsetAsync(s0, 0, (size_t)3 * B_ * K_ * 4, stream);

  project_k<<<dim3(I_), dim3(256), 0, stream>>>(x, W, uh);

  route_k<0><<<dim3(ICH, B_), dim3(256), 0, stream>>>(uh, nullptr, nullptr, nullptr, s0);
  squash_k<<<dim3(B_), dim3(256), 0, stream>>>(s0, bias, v0);

  route_k<1><<<dim3(ICH, B_), dim3(256), 0, stream>>>(uh, v0, nullptr, b1, s1);
  squash_k<<<dim3(B_), dim3(256), 0, stream>>>(s1, bias, v1);

  route_k<2><<<dim3(ICH, B_), dim3(256), 0, stream>>>(uh, v1, b1, nullptr, s2);
  squash_k<<<dim3(B_), dim3(256), 0, stream>>>(s2, bias, out);
}

// Round 2
// 275.667 us; speedup vs baseline: 1.3589x; 1.3589x over previous
//
#include <hip/hip_runtime.h>
#include <hip/hip_bf16.h>
#include <cstdio>

#define B_  64
#define I_  2048
#define J_  16
#define N_  64
#define D_  16
#define K_  1024   // N_*D_

typedef __attribute__((ext_vector_type(8))) unsigned short ushort8_t;

__device__ __forceinline__ float bf2f(unsigned short h) {
  return __uint_as_float(((unsigned int)h) << 16);
}
__device__ __forceinline__ unsigned short f2bf(float f) {
  unsigned int u = __float_as_uint(f);
  u += 0x7fffu + ((u >> 16) & 1u);   // RNE
  return (unsigned short)(u >> 16);
}

// One workgroup per in_capsule i. W[i] (16x1024) in registers (16 float4/thread).
// x rows for all 64 batches staged in LDS (4 KB) -> broadcast reads, latency-friendly.
__global__ __launch_bounds__(256) void project_k(const float* __restrict__ x,
                                                 const float* __restrict__ W,
                                                 unsigned short* __restrict__ uh) {
  const int i = blockIdx.x;
  const int t = threadIdx.x;          // k = 4t..4t+3

  __shared__ float xl[B_ * J_];       // 4 KB: x[b][i][j] for all b
#pragma unroll
  for (int r = 0; r < 4; ++r) {
    int idx = r * 256 + t;            // 0..1023
    xl[idx] = x[((size_t)(idx >> 4) * I_ + i) * J_ + (idx & 15)];
  }

  const float4* Wp = (const float4*)(W + (size_t)i * (J_ * K_));
  float4 w[J_];
#pragma unroll
  for (int j = 0; j < J_; ++j) w[j] = Wp[j * (K_ / 4) + t];

  __syncthreads();

#pragma unroll 2
  for (int b = 0; b < B_; ++b) {
    float4 acc = {0.f, 0.f, 0.f, 0.f};
#pragma unroll
    for (int j = 0; j < J_; ++j) {
      float xj = xl[b * J_ + j];      // LDS broadcast (uniform addr)
      acc.x += xj * w[j].x; acc.y += xj * w[j].y;
      acc.z += xj * w[j].z; acc.w += xj * w[j].w;
    }
    ushort4 s;
    s.x = f2bf(acc.x); s.y = f2bf(acc.y); s.z = f2bf(acc.z); s.w = f2bf(acc.w);
    *(ushort4*)(uh + ((size_t)b * I_ + i) * K_ + t * 4) = s;
  }
}

// Wave-local routing: lane = class capsule n; lane owns u[b,i,n*16..n*16+15].
// Softmax over n == 6-step __shfl_xor reduce across the wave. ZERO barriers in loop.
// Each wave: one b, 32 consecutive i. Block = 4 waves, same b; LDS-reduce then atomics.
// MODE 0: c = 1/64 exactly (softmax of zeros) -> plain sum * 1/64.
// MODE 1: logit = dot(u, v0)
// MODE 2: logit = dot(u, v0) + dot(u, v1)   (b1 recomputed, never materialized)
template <int MODE>
__global__ __launch_bounds__(256, 4) void route_k(const unsigned short* __restrict__ uh,
                                                  const float* __restrict__ va,
                                                  const float* __restrict__ vb,
                                                  float* __restrict__ s_out) {
  const int t    = threadIdx.x;
  const int lane = t & 63;            // = n
  const int wv   = t >> 6;            // 0..3
  const int b    = blockIdx.x >> 4;                 // 16 blocks per batch
  const int iw   = ((blockIdx.x & 15) << 2) + wv;   // 0..63
  const int i0   = iw * 32;                         // 32 i per wave

  float va_r[16], vb_r[16];
  if (MODE >= 1) {
#pragma unroll
    for (int q = 0; q < 4; ++q) {
      float4 tmp = *(const float4*)&va[(size_t)b * K_ + lane * 16 + q * 4];
      va_r[q*4+0] = tmp.x; va_r[q*4+1] = tmp.y; va_r[q*4+2] = tmp.z; va_r[q*4+3] = tmp.w;
    }
  }
  if (MODE == 2) {
#pragma unroll
    for (int q = 0; q < 4; ++q) {
      float4 tmp = *(const float4*)&vb[(size_t)b * K_ + lane * 16 + q * 4];
      vb_r[q*4+0] = tmp.x; vb_r[q*4+1] = tmp.y; vb_r[q*4+2] = tmp.z; vb_r[q*4+3] = tmp.w;
    }
  }

  constexpr int IPW = 32;
  constexpr int PF  = (MODE == 2) ? 2 : 4;   // prefetch depth (reg budget for MODE 2)

  const unsigned short* base = uh + (size_t)b * I_ * K_ + lane * 16;

  struct Row { ushort8_t lo, hi; };
  Row buf[PF];
#pragma unroll
  for (int p = 0; p < PF; ++p) {
    int ip = (i0 + p) & (I_ - 1);
    buf[p].lo = *(const ushort8_t*)(base + (size_t)ip * K_);
    buf[p].hi = *(const ushort8_t*)(base + (size_t)ip * K_ + 8);
  }

  float s_loc[16];
#pragma unroll
  for (int d = 0; d < 16; ++d) s_loc[d] = 0.f;

  for (int ii = 0; ii < IPW; ii += PF) {
#pragma unroll
    for (int p = 0; p < PF; ++p) {
      float u[16];
#pragma unroll
      for (int e = 0; e < 8; ++e) u[e]     = bf2f(buf[p].lo[e]);
#pragma unroll
      for (int e = 0; e < 8; ++e) u[8 + e] = bf2f(buf[p].hi[e]);

      // prefetch PF ahead (wrap mask keeps addr in-range; extra values unused)
      int ip = (i0 + ii + p + PF) & (I_ - 1);
      buf[p].lo = *(const ushort8_t*)(base + (size_t)ip * K_);
      buf[p].hi = *(const ushort8_t*)(base + (size_t)ip * K_ + 8);

      if (MODE == 0) {
#pragma unroll
        for (int d = 0; d < 16; ++d) s_loc[d] += u[d];
      } else {
        float bl = 0.f;
#pragma unroll
        for (int d = 0; d < 16; ++d) bl += u[d] * va_r[d];
        if (MODE == 2) {
          float b2 = 0.f;
#pragma unroll
          for (int d = 0; d < 16; ++d) b2 += u[d] * vb_r[d];
          bl += b2;
        }
        // softmax over the 64 lanes (n axis) — pure wave shuffles, no LDS
        float m = bl;
        m = fmaxf(m, __shfl_xor(m, 1));
        m = fmaxf(m, __shfl_xor(m, 2));
        m = fmaxf(m, __shfl_xor(m, 4));
        m = fmaxf(m, __shfl_xor(m, 8));
        m = fmaxf(m, __shfl_xor(m, 16));
        m = fmaxf(m, __shfl_xor(m, 32));
        float e = __expf(bl - m);
        float ss = e;
        ss += __shfl_xor(ss, 1);
        ss += __shfl_xor(ss, 2);
        ss += __shfl_xor(ss, 4);
        ss += __shfl_xor(ss, 8);
        ss += __shfl_xor(ss, 16);
        ss += __shfl_xor(ss, 32);
        float c = __fdividef(e, ss);
#pragma unroll
        for (int d = 0; d < 16; ++d) s_loc[d] += c * u[d];
      }
    }
  }

  if (MODE == 0) {
#pragma unroll
    for (int d = 0; d < 16; ++d) s_loc[d] *= (1.0f / 64.0f);
  }

  // block reduce (4 waves, same b) then one atomic set per block
  __shared__ float sred[4][64 * 17];   // pad 16->17: conflict-free elementwise
#pragma unroll
  for (int d = 0; d < 16; ++d) sred[wv][lane * 17 + d] = s_loc[d];
  __syncthreads();
#pragma unroll
  for (int e = 0; e < 4; ++e) {
    int idx = t * 4 + e;               // 0..1023
    int n = idx >> 4, d = idx & 15;
    float val = sred[0][n*17+d] + sred[1][n*17+d] + sred[2][n*17+d] + sred[3][n*17+d];
    atomicAdd(&s_out[(size_t)b * K_ + idx], val);
  }
}

// v = squash(s + bias)
__global__ __launch_bounds__(256) void squash_k(const float* __restrict__ s_in,
                                                const float* __restrict__ bias,
                                                float* __restrict__ v_out) {
  const int b = blockIdx.x, t = threadIdx.x, k0 = t * 4;
  float4 s = *(const float4*)&s_in[b * K_ + k0];
  float4 bb = *(const float4*)&bias[k0];
  s.x += bb.x; s.y += bb.y; s.z += bb.z; s.w += bb.w;
  float p = s.x * s.x + s.y * s.y + s.z * s.z + s.w * s.w;
  p += __shfl_xor(p, 1);
  p += __shfl_xor(p, 2);
  float n2 = p + 1e-7f;
  float nrm = sqrtf(n2);
  float f = nrm / (1.0f + n2);
  float4 o = {s.x * f, s.y * f, s.z * f, s.w * f};
  *(float4*)&v_out[b * K_ + k0] = o;
}

extern "C" void kernel_launch(void* const* d_in, const int* in_sizes, int n_in,
                              void* d_out, int out_size, void* d_ws, size_t ws_size,
                              hipStream_t stream) {
  const float* x    = (const float*)d_in[0];
  const float* W    = (const float*)d_in[1];
  const float* bias = (const float*)d_in[2];
  float* out = (float*)d_out;

  char* ws = (char*)d_ws;
  size_t off = 0;
  unsigned short* uh = (unsigned short*)(ws + off); off += (size_t)B_ * I_ * K_ * 2; // 268 MB
  float* s0 = (float*)(ws + off); off += (size_t)B_ * K_ * 4;
  float* s1 = (float*)(ws + off); off += (size_t)B_ * K_ * 4;
  float* s2 = (float*)(ws + off); off += (size_t)B_ * K_ * 4;
  float* v0 = (float*)(ws + off); off += (size_t)B_ * K_ * 4;
  float* v1 = (float*)(ws + off); off += (size_t)B_ * K_ * 4;

  if (ws_size < off)
    fprintf(stderr, "ClassCapsule: ws_size=%zu < needed=%zu — expect corruption\n", ws_size, off);

  hipMemsetAsync(s0, 0, (size_t)3 * B_ * K_ * 4, stream);  // s0,s1,s2 contiguous

  project_k<<<dim3(I_), dim3(256), 0, stream>>>(x, W, uh);

  route_k<0><<<dim3(1024), dim3(256), 0, stream>>>(uh, nullptr, nullptr, s0);
  squash_k<<<dim3(B_), dim3(256), 0, stream>>>(s0, bias, v0);

  route_k<1><<<dim3(1024), dim3(256), 0, stream>>>(uh, v0, nullptr, s1);
  squash_k<<<dim3(B_), dim3(256), 0, stream>>>(s1, bias, v1);

  route_k<2><<<dim3(1024), dim3(256), 0, stream>>>(uh, v0, v1, s2);
  squash_k<<<dim3(B_), dim3(256), 0, stream>>>(s2, bias, out);
}

// Round 3
// 247.667 us; speedup vs baseline: 1.5126x; 1.1131x over previous
//
#include <hip/hip_runtime.h>
#include <hip/hip_bf16.h>
#include <cstdio>

#define B_  64
#define I_  2048
#define J_  16
#define N_  64
#define D_  16
#define K_  1024   // N_*D_

typedef __attribute__((ext_vector_type(8))) unsigned short ushort8_t;

__device__ __forceinline__ float bf2f(unsigned short h) {
  return __uint_as_float(((unsigned int)h) << 16);
}
__device__ __forceinline__ unsigned short f2bf(float f) {
  unsigned int u = __float_as_uint(f);
  u += 0x7fffu + ((u >> 16) & 1u);   // RNE
  return (unsigned short)(u >> 16);
}

// Block = (i, half of b). W[i] slice in registers (16 float4/thread), x rows in LDS
// read as ds_read_b128 broadcasts, 2-stage software pipeline (next-b x loads issued
// before current-b FMAs) so LDS latency hides under the 64-FMA body.
__global__ __launch_bounds__(256) void project_k(const float* __restrict__ x,
                                                 const float* __restrict__ W,
                                                 unsigned short* __restrict__ uh) {
  const int i  = blockIdx.x >> 1;
  const int b0 = (blockIdx.x & 1) * 32;
  const int t  = threadIdx.x;

  __shared__ float4 xl[32 * 4];        // 2 KB: x[b0+bb][i][0..15] as 4 float4 per b
  if (t < 128) {
    int bb = t >> 2, q = t & 3;
    xl[t] = ((const float4*)(x + ((size_t)(b0 + bb) * I_ + i) * J_))[q];
  }

  const float4* Wp = (const float4*)(W + (size_t)i * (J_ * K_));
  float4 w[J_];
#pragma unroll
  for (int j = 0; j < J_; ++j) w[j] = Wp[j * (K_ / 4) + t];

  __syncthreads();

  unsigned short* op = uh + (size_t)b0 * I_ * K_ + (size_t)i * K_ + t * 4;

  float4 xa0 = xl[0], xa1 = xl[1], xa2 = xl[2], xa3 = xl[3];
  for (int bb = 0; bb < 32; ++bb) {
    float4 xb0, xb1, xb2, xb3;
    if (bb < 31) {                      // prefetch next b's x (4x ds_read_b128)
      xb0 = xl[(bb + 1) * 4 + 0]; xb1 = xl[(bb + 1) * 4 + 1];
      xb2 = xl[(bb + 1) * 4 + 2]; xb3 = xl[(bb + 1) * 4 + 3];
    }
    float4 acc = {0.f, 0.f, 0.f, 0.f};
#define FMA4(xc, j0)  \
    acc.x += xc.x * w[j0].x;     acc.y += xc.x * w[j0].y;     acc.z += xc.x * w[j0].z;     acc.w += xc.x * w[j0].w; \
    acc.x += xc.y * w[j0+1].x;   acc.y += xc.y * w[j0+1].y;   acc.z += xc.y * w[j0+1].z;   acc.w += xc.y * w[j0+1].w; \
    acc.x += xc.z * w[j0+2].x;   acc.y += xc.z * w[j0+2].y;   acc.z += xc.z * w[j0+2].z;   acc.w += xc.z * w[j0+2].w; \
    acc.x += xc.w * w[j0+3].x;   acc.y += xc.w * w[j0+3].y;   acc.z += xc.w * w[j0+3].z;   acc.w += xc.w * w[j0+3].w;
    FMA4(xa0, 0) FMA4(xa1, 4) FMA4(xa2, 8) FMA4(xa3, 12)
#undef FMA4
    ushort4 s;
    s.x = f2bf(acc.x); s.y = f2bf(acc.y); s.z = f2bf(acc.z); s.w = f2bf(acc.w);
    *(ushort4*)op = s;
    op += (size_t)I_ * K_;
    xa0 = xb0; xa1 = xb1; xa2 = xb2; xa3 = xb3;
  }
}

// Wave-local routing: lane = class capsule n; lane owns u[b,i,n*16..n*16+15].
// Softmax over n == 6-step __shfl_xor reduce. ZERO barriers in main loop.
// squash(v) is computed INLINE from the raw s buffers (lane-local: 16 d per lane).
// MODE 0: c = 1/64 exactly -> plain sum * 1/64.
// MODE 1: logit = dot(u, v0),          v0 = squash(sa + bias)
// MODE 2: logit = dot(u, v0)+dot(u,v1) (b-logits recomputed, never materialized)
template <int MODE>
__global__ __launch_bounds__(256, 4) void route_k(const unsigned short* __restrict__ uh,
                                                  const float* __restrict__ sa,
                                                  const float* __restrict__ sb,
                                                  const float* __restrict__ bias,
                                                  float* __restrict__ s_out) {
  const int t    = threadIdx.x;
  const int lane = t & 63;            // = n
  const int wv   = t >> 6;            // 0..3
  const int b    = blockIdx.x >> 4;                 // 16 blocks per batch
  const int iw   = ((blockIdx.x & 15) << 2) + wv;   // 0..63
  const int i0   = iw * 32;                         // 32 i per wave

  float va_r[16], vb_r[16];
  if (MODE >= 1) {
    float bs[16];
#pragma unroll
    for (int q = 0; q < 4; ++q) {
      float4 bb4 = *(const float4*)&bias[lane * 16 + q * 4];
      bs[q*4+0] = bb4.x; bs[q*4+1] = bb4.y; bs[q*4+2] = bb4.z; bs[q*4+3] = bb4.w;
    }
    // va = squash(sa + bias), lane-local over 16 d
    {
      float nn = 0.f;
#pragma unroll
      for (int q = 0; q < 4; ++q) {
        float4 tmp = *(const float4*)&sa[(size_t)b * K_ + lane * 16 + q * 4];
        va_r[q*4+0] = tmp.x + bs[q*4+0]; va_r[q*4+1] = tmp.y + bs[q*4+1];
        va_r[q*4+2] = tmp.z + bs[q*4+2]; va_r[q*4+3] = tmp.w + bs[q*4+3];
      }
#pragma unroll
      for (int d = 0; d < 16; ++d) nn += va_r[d] * va_r[d];
      float n2 = nn + 1e-7f;
      float f = sqrtf(n2) / (1.0f + n2);
#pragma unroll
      for (int d = 0; d < 16; ++d) va_r[d] *= f;
    }
    if (MODE == 2) {
      float nn = 0.f;
#pragma unroll
      for (int q = 0; q < 4; ++q) {
        float4 tmp = *(const float4*)&sb[(size_t)b * K_ + lane * 16 + q * 4];
        vb_r[q*4+0] = tmp.x + bs[q*4+0]; vb_r[q*4+1] = tmp.y + bs[q*4+1];
        vb_r[q*4+2] = tmp.z + bs[q*4+2]; vb_r[q*4+3] = tmp.w + bs[q*4+3];
      }
#pragma unroll
      for (int d = 0; d < 16; ++d) nn += vb_r[d] * vb_r[d];
      float n2 = nn + 1e-7f;
      float f = sqrtf(n2) / (1.0f + n2);
#pragma unroll
      for (int d = 0; d < 16; ++d) vb_r[d] *= f;
    }
  }

  constexpr int IPW = 32;
  constexpr int PF  = (MODE == 2) ? 2 : 4;   // prefetch depth

  const unsigned short* base = uh + (size_t)b * I_ * K_ + lane * 16;

  struct Row { ushort8_t lo, hi; };
  Row buf[PF];
#pragma unroll
  for (int p = 0; p < PF; ++p) {
    int ip = (i0 + p) & (I_ - 1);
    buf[p].lo = *(const ushort8_t*)(base + (size_t)ip * K_);
    buf[p].hi = *(const ushort8_t*)(base + (size_t)ip * K_ + 8);
  }

  float s_loc[16];
#pragma unroll
  for (int d = 0; d < 16; ++d) s_loc[d] = 0.f;

  for (int ii = 0; ii < IPW; ii += PF) {
#pragma unroll
    for (int p = 0; p < PF; ++p) {
      float u[16];
#pragma unroll
      for (int e = 0; e < 8; ++e) u[e]     = bf2f(buf[p].lo[e]);
#pragma unroll
      for (int e = 0; e < 8; ++e) u[8 + e] = bf2f(buf[p].hi[e]);

      int ip = (i0 + ii + p + PF) & (I_ - 1);
      buf[p].lo = *(const ushort8_t*)(base + (size_t)ip * K_);
      buf[p].hi = *(const ushort8_t*)(base + (size_t)ip * K_ + 8);

      if (MODE == 0) {
#pragma unroll
        for (int d = 0; d < 16; ++d) s_loc[d] += u[d];
      } else {
        float bl = 0.f;
#pragma unroll
        for (int d = 0; d < 16; ++d) bl += u[d] * va_r[d];
        if (MODE == 2) {
          float b2 = 0.f;
#pragma unroll
          for (int d = 0; d < 16; ++d) b2 += u[d] * vb_r[d];
          bl += b2;
        }
        float m = bl;
        m = fmaxf(m, __shfl_xor(m, 1));
        m = fmaxf(m, __shfl_xor(m, 2));
        m = fmaxf(m, __shfl_xor(m, 4));
        m = fmaxf(m, __shfl_xor(m, 8));
        m = fmaxf(m, __shfl_xor(m, 16));
        m = fmaxf(m, __shfl_xor(m, 32));
        float e = __expf(bl - m);
        float ss = e;
        ss += __shfl_xor(ss, 1);
        ss += __shfl_xor(ss, 2);
        ss += __shfl_xor(ss, 4);
        ss += __shfl_xor(ss, 8);
        ss += __shfl_xor(ss, 16);
        ss += __shfl_xor(ss, 32);
        float c = __fdividef(e, ss);
#pragma unroll
        for (int d = 0; d < 16; ++d) s_loc[d] += c * u[d];
      }
    }
  }

  if (MODE == 0) {
#pragma unroll
    for (int d = 0; d < 16; ++d) s_loc[d] *= (1.0f / 64.0f);
  }

  // block reduce (4 waves, same b) then atomics
  __shared__ float sred[4][64 * 17];
#pragma unroll
  for (int d = 0; d < 16; ++d) sred[wv][lane * 17 + d] = s_loc[d];
  __syncthreads();
#pragma unroll
  for (int e = 0; e < 4; ++e) {
    int idx = t * 4 + e;               // 0..1023
    int n = idx >> 4, d = idx & 15;
    float val = sred[0][n*17+d] + sred[1][n*17+d] + sred[2][n*17+d] + sred[3][n*17+d];
    atomicAdd(&s_out[(size_t)b * K_ + idx], val);
  }
}

// final output only: v = squash(s + bias)
__global__ __launch_bounds__(256) void squash_k(const float* __restrict__ s_in,
                                                const float* __restrict__ bias,
                                                float* __restrict__ v_out) {
  const int b = blockIdx.x, t = threadIdx.x, k0 = t * 4;
  float4 s = *(const float4*)&s_in[b * K_ + k0];
  float4 bb = *(const float4*)&bias[k0];
  s.x += bb.x; s.y += bb.y; s.z += bb.z; s.w += bb.w;
  float p = s.x * s.x + s.y * s.y + s.z * s.z + s.w * s.w;
  p += __shfl_xor(p, 1);
  p += __shfl_xor(p, 2);
  float n2 = p + 1e-7f;
  float nrm = sqrtf(n2);
  float f = nrm / (1.0f + n2);
  float4 o = {s.x * f, s.y * f, s.z * f, s.w * f};
  *(float4*)&v_out[b * K_ + k0] = o;
}

extern "C" void kernel_launch(void* const* d_in, const int* in_sizes, int n_in,
                              void* d_out, int out_size, void* d_ws, size_t ws_size,
                              hipStream_t stream) {
  const float* x    = (const float*)d_in[0];
  const float* W    = (const float*)d_in[1];
  const float* bias = (const float*)d_in[2];
  float* out = (float*)d_out;

  char* ws = (char*)d_ws;
  size_t off = 0;
  unsigned short* uh = (unsigned short*)(ws + off); off += (size_t)B_ * I_ * K_ * 2; // 268 MB
  float* s0 = (float*)(ws + off); off += (size_t)B_ * K_ * 4;
  float* s1 = (float*)(ws + off); off += (size_t)B_ * K_ * 4;
  float* s2 = (float*)(ws + off); off += (size_t)B_ * K_ * 4;

  if (ws_size < off)
    fprintf(stderr, "ClassCapsule: ws_size=%zu < needed=%zu — expect corruption\n", ws_size, off);

  hipMemsetAsync(s0, 0, (size_t)3 * B_ * K_ * 4, stream);  // s0,s1,s2 contiguous

  project_k<<<dim3(I_ * 2), dim3(256), 0, stream>>>(x, W, uh);

  route_k<0><<<dim3(1024), dim3(256), 0, stream>>>(uh, nullptr, nullptr, bias, s0);
  route_k<1><<<dim3(1024), dim3(256), 0, stream>>>(uh, s0, nullptr, bias, s1);
  route_k<2><<<dim3(1024), dim3(256), 0, stream>>>(uh, s0, s1, bias, s2);
  squash_k<<<dim3(B_), dim3(256), 0, stream>>>(s2, bias, out);
}